// Round 1
// baseline (273.344 us; speedup 1.0000x reference)
//
#include <hip/hip_runtime.h>
#include <stdint.h>

#define CC 256
#define NN 4096

typedef float f32x4 __attribute__((ext_vector_type(4)));
typedef short bf16x8 __attribute__((ext_vector_type(8)));
typedef unsigned int u32x4 __attribute__((ext_vector_type(4)));

#define MFMA16(a, b, c) __builtin_amdgcn_mfma_f32_16x16x32_bf16(a, b, c, 0, 0, 0)

static __device__ __forceinline__ short f2bf(float f) {
  unsigned u = __builtin_bit_cast(unsigned, f);
  u += 0x7fffu + ((u >> 16) & 1u);   // RNE
  return (short)(u >> 16);
}
static __device__ __forceinline__ float bf2f(short s) {
  return __builtin_bit_cast(float, ((unsigned)(unsigned short)s) << 16);
}

// ---------------------------------------------------------------------------
// Kernel 1: projections.
//  - q,k: split hi/lo bf16, packed (lo<<16)|hi u32, layout [B][N][32]; q scaled
//    by log2(e) so energies come out in log2 domain.
//  - v: bf16, layout [B][C][N].
// A = W rows (contiguous), B = x tile staged in LDS (stride-padded, 2-way max).
// 3-MFMA split per product keeps q/k at ~fp32 accuracy.
// ---------------------------------------------------------------------------
#define XSTR 66

__global__ __launch_bounds__(256) void proj_kernel(
    const float* __restrict__ x,
    const float* __restrict__ Wq, const float* __restrict__ bq,
    const float* __restrict__ Wk, const float* __restrict__ bk,
    const float* __restrict__ Wv, const float* __restrict__ bv,
    unsigned* __restrict__ qpack, unsigned* __restrict__ kpack,
    unsigned short* __restrict__ vbf)
{
  __shared__ float xs[256 * XSTR];
  const int t = threadIdx.x;
  const int b = blockIdx.x >> 6;
  const int n0 = (blockIdx.x & 63) << 6;
  const float L2E = 1.4426950408889634f;

  // stage x[b][:, n0:n0+64] into LDS (coalesced float4 loads)
  const float* xb = x + ((size_t)b * CC) * NN + n0;
#pragma unroll
  for (int i = 0; i < 16; ++i) {
    int fi = i * 256 + t;
    int c = fi >> 4, nv = (fi & 15) << 2;
    float4 v4 = *(const float4*)(xb + (size_t)c * NN + nv);
    float* d = &xs[c * XSTR + nv];
    d[0] = v4.x; d[1] = v4.y; d[2] = v4.z; d[3] = v4.w;
  }
  __syncthreads();

  const int w = t >> 6, l = t & 63;
  const int l15 = l & 15, l4 = l >> 4;

  // 20 row-tiles total: 16 v + 2 q + 2 k ; wave w owns tiles w*5 .. w*5+4
  f32x4 acc[5][4];
#pragma unroll
  for (int r5 = 0; r5 < 5; ++r5) {
    int rt = w * 5 + r5;
    const float* bias; float bscale;
    if (rt < 16)      { bias = bv + rt * 16;        bscale = 1.f; }
    else if (rt < 18) { bias = bq + (rt - 16) * 16; bscale = L2E; }
    else              { bias = bk + (rt - 18) * 16; bscale = 1.f; }
#pragma unroll
    for (int j = 0; j < 4; ++j) {
      float bval = bias[l4 * 4 + j] * bscale;
#pragma unroll
      for (int nt = 0; nt < 4; ++nt) acc[r5][nt][j] = bval;
    }
  }

#pragma unroll 1
  for (int ks = 0; ks < 8; ++ks) {
    bf16x8 ah[5], al[5];
#pragma unroll
    for (int r5 = 0; r5 < 5; ++r5) {
      int rt = w * 5 + r5;
      const float* wrow; float wscale;
      if (rt < 16)      { wrow = Wv + (size_t)(rt * 16 + l15) * 256;        wscale = 1.f; }
      else if (rt < 18) { wrow = Wq + (size_t)((rt - 16) * 16 + l15) * 256; wscale = L2E; }
      else              { wrow = Wk + (size_t)((rt - 18) * 16 + l15) * 256; wscale = 1.f; }
      const float* src = wrow + ks * 32 + l4 * 8;
#pragma unroll
      for (int i = 0; i < 8; ++i) {
        float v = src[i] * wscale;
        short hh = f2bf(v);
        ah[r5][i] = hh;
        al[r5][i] = f2bf(v - bf2f(hh));
      }
    }
#pragma unroll
    for (int nt = 0; nt < 4; ++nt) {
      bf16x8 bh, bl;
#pragma unroll
      for (int i = 0; i < 8; ++i) {
        float v = xs[(ks * 32 + l4 * 8 + i) * XSTR + nt * 16 + l15];
        short hh = f2bf(v);
        bh[i] = hh;
        bl[i] = f2bf(v - bf2f(hh));
      }
#pragma unroll
      for (int r5 = 0; r5 < 5; ++r5) {
        acc[r5][nt] = MFMA16(ah[r5], bl, acc[r5][nt]);
        acc[r5][nt] = MFMA16(al[r5], bh, acc[r5][nt]);
        acc[r5][nt] = MFMA16(ah[r5], bh, acc[r5][nt]);
      }
    }
  }

  // stores
#pragma unroll
  for (int r5 = 0; r5 < 5; ++r5) {
    int rt = w * 5 + r5;
#pragma unroll
    for (int nt = 0; nt < 4; ++nt) {
      int n = n0 + nt * 16 + l15;
#pragma unroll
      for (int j = 0; j < 4; ++j) {
        float v = acc[r5][nt][j];
        int sub = l4 * 4 + j;
        if (rt < 16) {
          int c = rt * 16 + sub;
          vbf[((size_t)b * CC + c) * NN + n] = (unsigned short)f2bf(v);
        } else {
          short hh = f2bf(v);
          short lo = f2bf(v - bf2f(hh));
          unsigned u = ((unsigned)(unsigned short)lo << 16) | (unsigned short)hh;
          unsigned* dst = (rt < 18) ? qpack : kpack;
          int d = ((rt < 18) ? (rt - 16) : (rt - 18)) * 16 + sub;
          dst[((size_t)b * NN + n) * 32 + d] = u;
        }
      }
    }
  }
}

// ---------------------------------------------------------------------------
// Kernel 2: fused attention. Block = (b, 32 rows). 4 waves.
//  E-phase roles: wave (g = rows group of 16, h = m-half of 16).
//  PV-phase roles: wave = c-quarter of 64 channels.
//  Pass 1: streaming split-MFMA energy + per-lane online max/sumexp.
//  Pass 2: recompute energy, write attention fp32, p -> swizzled LDS,
//          PV bf16 MFMA with v fragments prefetched from L2.
// ---------------------------------------------------------------------------
__global__ __launch_bounds__(256) void attn_kernel(
    const float* __restrict__ x,
    const unsigned* __restrict__ qpack, const unsigned* __restrict__ kpack,
    const unsigned short* __restrict__ vbf,
    const float* __restrict__ gamma, float* __restrict__ out)
{
  __shared__ unsigned short p_lds[2][1024];   // 2 x [32 rows][32 m] bf16, XOR-swizzled
  __shared__ float stats_lds[2][32][2];

  const int t = threadIdx.x;
  // XCD swizzle: 512 blocks -> 64 consecutive logical ids per XCD (same b per XCD pair)
  const int sbid = ((blockIdx.x & 7) << 6) | (blockIdx.x >> 3);
  const int b = sbid >> 7;
  const int n0 = (sbid & 127) << 5;
  const int w = t >> 6, l = t & 63;
  const int l15 = l & 15, l4 = l >> 4;
  const int g = w >> 1, h = w & 1;
  const int koff = l4 * 8;

  // q fragments (A operand: row = l15 -> n, k = l4*8+i -> d), invariant
  const unsigned* qrow = qpack + ((size_t)b * NN + n0 + g * 16 + l15) * 32 + koff;
  u32x4 qa = *(const u32x4*)qrow;
  u32x4 qb = *(const u32x4*)(qrow + 4);
  bf16x8 qh, ql;
#pragma unroll
  for (int i = 0; i < 4; ++i) {
    qh[i]     = (short)(qa[i] & 0xffff); ql[i]     = (short)(qa[i] >> 16);
    qh[i + 4] = (short)(qb[i] & 0xffff); ql[i + 4] = (short)(qb[i] >> 16);
  }

  const unsigned* kb_ = kpack + (size_t)b * NN * 32;

  // ---------------- pass 1: row max / sum-exp (log2 domain) ----------------
  float mx[4], sx[4];
#pragma unroll
  for (int j = 0; j < 4; ++j) { mx[j] = -1e30f; sx[j] = 0.f; }

  u32x4 ka  = *(const u32x4*)(kb_ + (size_t)(h * 16 + l15) * 32 + koff);
  u32x4 kb2 = *(const u32x4*)(kb_ + (size_t)(h * 16 + l15) * 32 + koff + 4);
#pragma unroll 1
  for (int c0 = 0; c0 < NN; c0 += 32) {
    u32x4 na = ka, nb = kb2;
    if (c0 + 32 < NN) {
      const unsigned* kp = kb_ + (size_t)(c0 + 32 + h * 16 + l15) * 32 + koff;
      na = *(const u32x4*)kp;
      nb = *(const u32x4*)(kp + 4);
    }
    bf16x8 kh, kl;
#pragma unroll
    for (int i = 0; i < 4; ++i) {
      kh[i]     = (short)(ka[i] & 0xffff); kl[i]     = (short)(ka[i] >> 16);
      kh[i + 4] = (short)(kb2[i] & 0xffff); kl[i + 4] = (short)(kb2[i] >> 16);
    }
    f32x4 e = {0.f, 0.f, 0.f, 0.f};
    e = MFMA16(qh, kl, e);
    e = MFMA16(ql, kh, e);
    e = MFMA16(qh, kh, e);
#pragma unroll
    for (int j = 0; j < 4; ++j) {
      float ev = e[j];
      bool gt = ev > mx[j];
      float mn = gt ? ev : mx[j];
      float ot = gt ? mx[j] : ev;
      float tt = exp2f(ot - mn);
      sx[j] = gt ? __builtin_fmaf(sx[j], tt, 1.0f) : (sx[j] + tt);
      mx[j] = mn;
    }
    ka = na; kb2 = nb;
  }
  // reduce over the 16 m-lanes
#pragma unroll
  for (int mask = 1; mask < 16; mask <<= 1) {
#pragma unroll
    for (int j = 0; j < 4; ++j) {
      float om = __shfl_xor(mx[j], mask);
      float os = __shfl_xor(sx[j], mask);
      float mn = fmaxf(mx[j], om);
      sx[j] = sx[j] * exp2f(mx[j] - mn) + os * exp2f(om - mn);
      mx[j] = mn;
    }
  }
  if (l15 == 0) {
#pragma unroll
    for (int j = 0; j < 4; ++j) {
      int r = g * 16 + l4 * 4 + j;
      stats_lds[h][r][0] = mx[j];
      stats_lds[h][r][1] = sx[j];
    }
  }
  __syncthreads();
  float M[4], invS[4];
#pragma unroll
  for (int j = 0; j < 4; ++j) {
    int r = g * 16 + l4 * 4 + j;
    float m0 = stats_lds[0][r][0], s0 = stats_lds[0][r][1];
    float m1 = stats_lds[1][r][0], s1 = stats_lds[1][r][1];
    float mn = fmaxf(m0, m1);
    float S = s0 * exp2f(m0 - mn) + s1 * exp2f(m1 - mn);
    M[j] = mn;
    invS[j] = 1.0f / S;
  }

  // ---------------- pass 2: attention out + PV ----------------
  f32x4 acc[4][2];
#pragma unroll
  for (int ct = 0; ct < 4; ++ct)
#pragma unroll
    for (int nt = 0; nt < 2; ++nt)
      acc[ct][nt] = f32x4{0.f, 0.f, 0.f, 0.f};

  float* attn = out + 8388608 + (size_t)b * NN * NN;
  const unsigned short* vb = vbf + (size_t)b * CC * NN;

  ka  = *(const u32x4*)(kb_ + (size_t)(h * 16 + l15) * 32 + koff);
  kb2 = *(const u32x4*)(kb_ + (size_t)(h * 16 + l15) * 32 + koff + 4);
  int par = 0;
#pragma unroll 1
  for (int c0 = 0; c0 < NN; c0 += 32, par ^= 1) {
    // issue v fragment loads early (consumed after the barrier)
    u32x4 vfr[4];
#pragma unroll
    for (int ct = 0; ct < 4; ++ct) {
      int crow = w * 64 + ct * 16 + l15;
      vfr[ct] = *(const u32x4*)(vb + (size_t)crow * NN + c0 + koff);
    }
    u32x4 na = ka, nb = kb2;
    if (c0 + 32 < NN) {
      const unsigned* kp = kb_ + (size_t)(c0 + 32 + h * 16 + l15) * 32 + koff;
      na = *(const u32x4*)kp;
      nb = *(const u32x4*)(kp + 4);
    }
    bf16x8 kh, kl;
#pragma unroll
    for (int i = 0; i < 4; ++i) {
      kh[i]     = (short)(ka[i] & 0xffff); kl[i]     = (short)(ka[i] >> 16);
      kh[i + 4] = (short)(kb2[i] & 0xffff); kl[i + 4] = (short)(kb2[i] >> 16);
    }
    f32x4 e = {0.f, 0.f, 0.f, 0.f};
    e = MFMA16(qh, kl, e);
    e = MFMA16(ql, kh, e);
    e = MFMA16(qh, kh, e);
#pragma unroll
    for (int j = 0; j < 4; ++j) {
      float p = exp2f(e[j] - M[j]) * invS[j];
      int n = n0 + g * 16 + l4 * 4 + j;
      int m = c0 + h * 16 + l15;
      attn[(size_t)n * NN + m] = p;
      int nl = g * 16 + l4 * 4 + j;
      int byteo = nl * 64 + ((((h * 16 + l15) * 2)) ^ (((nl >> 2) & 3) << 4));
      *(unsigned short*)((char*)p_lds[par] + byteo) = (unsigned short)f2bf(p);
    }
    __syncthreads();
    // PV: D[c][n] += v[c][m] * p[n][m]^T
#pragma unroll
    for (int nt = 0; nt < 2; ++nt) {
      int nl = nt * 16 + l15;
      int byteo = nl * 64 + ((l4 * 16) ^ (((nl >> 2) & 3) << 4));
      bf16x8 pb = *(const bf16x8*)((const char*)p_lds[par] + byteo);
#pragma unroll
      for (int ct = 0; ct < 4; ++ct) {
        acc[ct][nt] = MFMA16(__builtin_bit_cast(bf16x8, vfr[ct]), pb, acc[ct][nt]);
      }
    }
    ka = na; kb2 = nb;
  }

  // epilogue: weighted_out = gamma*out ; final = x + weighted_out
  float gm = gamma[0];
#pragma unroll
  for (int ct = 0; ct < 4; ++ct) {
#pragma unroll
    for (int nt = 0; nt < 2; ++nt) {
#pragma unroll
      for (int j = 0; j < 4; ++j) {
        int c = w * 64 + ct * 16 + l4 * 4 + j;
        int n = n0 + nt * 16 + l15;
        size_t idx = ((size_t)b * CC + c) * NN + n;
        float o = acc[ct][nt][j] * gm;
        out[4194304 + idx] = o;
        out[idx] = o + x[idx];
      }
    }
  }
}

extern "C" void kernel_launch(void* const* d_in, const int* in_sizes, int n_in,
                              void* d_out, int out_size, void* d_ws, size_t ws_size,
                              hipStream_t stream) {
  const float* x     = (const float*)d_in[0];
  const float* Wq    = (const float*)d_in[1];
  const float* bq    = (const float*)d_in[2];
  const float* Wk    = (const float*)d_in[3];
  const float* bk    = (const float*)d_in[4];
  const float* Wv    = (const float*)d_in[5];
  const float* bv    = (const float*)d_in[6];
  const float* gamma = (const float*)d_in[7];
  float* out = (float*)d_out;

  unsigned* qpack      = (unsigned*)d_ws;                            // 2 MB
  unsigned* kpack      = (unsigned*)((char*)d_ws + (2u << 20));      // 2 MB
  unsigned short* vbf  = (unsigned short*)((char*)d_ws + (4u << 20));// 8 MB

  proj_kernel<<<256, 256, 0, stream>>>(x, Wq, bq, Wk, bk, Wv, bv, qpack, kpack, vbf);
  attn_kernel<<<512, 256, 0, stream>>>(x, qpack, kpack, vbf, gamma, out);
}